// Round 13
// baseline (43.935 us; speedup 1.0000x reference)
//
#include <hip/hip_runtime.h>

// Problem constants (from reference): B=16, L=4096, D=1024, K=64
#define Bn 16
#define Ln 4096
#define Dn 1024
#define Kn 64
#define CH 16                  // tokens per fine chunk (slot granularity)
#define SEGTOK 128             // tokens per segment (one stream block)
#define CPS (SEGTOK / CH)      // 8 chunks per segment
#define NSEG (Ln / SEGTOK)     // 32 segments per batch row
#define SLOTS (CPS + 1)        // 9 slots: excl prefix at chunk j, slot 8 = seg total
#define NSPAN (2 * Bn * Kn)    // 2048 span ints
#define NSMALL (Bn + 1)        // am-prefix blocks + decode block (dispatched first)

static __device__ __forceinline__ void acc4(float4& a, const float4 v) {
    a.x += v.x; a.y += v.y; a.z += v.z; a.w += v.w;
}
static __device__ __forceinline__ void sub4(float4& a, const float4 v) {
    a.x -= v.x; a.y -= v.y; a.z -= v.z; a.w -= v.w;
}
static __device__ __forceinline__ void acc4w(float4& a, const float4 v, float w) {
    a.x += v.x * w; a.y += v.y * w; a.z += v.z * w; a.w += v.w * w;
}

// ---------------------------------------------------------------------------
// K1 (fused stream + scan, branch-free weighted loads):
// grid = NSMALL small blocks (FIRST, so they don't tail) + B*NSEG segment
// blocks. Segment block: per 16-token chunk, effective index le[t] = last
// attended token <= t (cndmask chain); all 16 row loads unconditional
// (duplicates hit L1), w=0 kills duplicate contributions exactly.
// Running weighted sum -> exclusive intra-segment prefix slots + seg total.
// ---------------------------------------------------------------------------
__global__ __launch_bounds__(256) void fused_stage1_kernel(
    const float* __restrict__ x, const int* __restrict__ am,
    const unsigned int* __restrict__ spans_raw,
    float* __restrict__ Pf, int* __restrict__ Pam, int* __restrict__ dec) {
    const int bc = blockIdx.x;

    if (bc >= NSMALL) {
        // ---- segment stream + intra-segment prefix ----
        const int bcs = bc - NSMALL;
        const int b = bcs / NSEG;
        const int seg = bcs % NSEG;
        const int d0 = threadIdx.x * 4;

        const float* xp = x + ((size_t)b * Ln + (size_t)seg * SEGTOK) * Dn + d0;
        const int* amp = am + b * Ln + seg * SEGTOK;
        float* pf = Pf + (size_t)bcs * SLOTS * Dn + d0;

        float4 acc = {0.f, 0.f, 0.f, 0.f};
#pragma unroll
        for (int j = 0; j < CPS; ++j) {
            *(float4*)(pf + (size_t)j * Dn) = acc;   // exclusive prefix slot j

            int wv[CH];
#pragma unroll
            for (int t = 0; t < CH; ++t) wv[t] = amp[j * CH + t];

            int any = 0;
#pragma unroll
            for (int t = 0; t < CH; ++t) any |= wv[t];

            if (any != 0) {                          // ~always taken
                int f = 0;
#pragma unroll
                for (int t = CH - 1; t >= 0; --t) if (wv[t] != 0) f = t;
                int le[CH];
                int lp = f;
#pragma unroll
                for (int t = 0; t < CH; ++t) {
                    lp = (wv[t] != 0) ? t : lp;
                    le[t] = lp;
                }
                float4 v[CH];
#pragma unroll
                for (int t = 0; t < CH; ++t)
                    v[t] = *(const float4*)(xp + (size_t)(j * CH + le[t]) * Dn);
                float4 s0 = {0.f, 0.f, 0.f, 0.f}, s1 = {0.f, 0.f, 0.f, 0.f};
#pragma unroll
                for (int t = 0; t < CH; t += 2) {
                    acc4w(s0, v[t],     (float)wv[t]);
                    acc4w(s1, v[t + 1], (float)wv[t + 1]);
                }
                acc4(s0, s1);
                acc4(acc, s0);
            }
        }
        *(float4*)(pf + (size_t)CPS * Dn) = acc;     // segment total
    } else if (bc < Bn) {
        // ---- am token-prefix for batch b (dispatched first) ----
        const int b = bc;
        const int t = threadIdx.x;
        const int i0 = t * 16;
        const int* amb = am + (size_t)b * Ln;
        int loc[16];
        int lsum = 0;
#pragma unroll
        for (int j = 0; j < 16; ++j) { loc[j] = amb[i0 + j]; lsum += loc[j]; }

        __shared__ int ssum[256];
        ssum[t] = lsum;
        __syncthreads();
        for (int off = 1; off < 256; off <<= 1) {
            int v2 = (t >= off) ? ssum[t - off] : 0;
            __syncthreads();
            ssum[t] += v2;
            __syncthreads();
        }
        int run = ssum[t] - lsum;                    // exclusive offset
        int* pam = Pam + (size_t)b * (Ln + 1);
#pragma unroll
        for (int j = 0; j < 16; ++j) { pam[i0 + j] = run; run += loc[j]; }
        if (t == 255) pam[Ln] = run;
    } else {
        // ---- span decode (block Bn) ----
        __shared__ unsigned int sred[256];
        unsigned int acc = 0;
        for (int i = threadIdx.x; i < NSPAN / 2; i += 256)
            acc |= spans_raw[2 * i + 1];
        sred[threadIdx.x] = acc;
        __syncthreads();
        for (int off = 128; off > 0; off >>= 1) {
            if ((int)threadIdx.x < off) sred[threadIdx.x] |= sred[threadIdx.x + off];
            __syncthreads();
        }
        const bool is64 = (sred[0] == 0u);
        for (int i = threadIdx.x; i < NSPAN; i += 256)
            dec[i] = is64 ? (int)spans_raw[2 * i] : (int)spans_raw[i];
    }
}

// ---------------------------------------------------------------------------
// K2: per-span pooling. grid = B*K blocks, 256 threads, no syncthreads.
// mask_sum = Pam[e]-Pam[s]. Edge sides are prepped together and BOTH load
// batches are issued before the interior Pf work (loads in flight overlap
// the L2-resident interior reads); FMAs consume afterwards. Branch-free
// effective-index pattern per side; w=0 kills duplicates exactly.
// ---------------------------------------------------------------------------
__global__ __launch_bounds__(256) void span_pool_kernel(
    const float* __restrict__ x, const int* __restrict__ am,
    const int* __restrict__ spans, const float* __restrict__ Pf,
    const int* __restrict__ Pam, float* __restrict__ H,
    float* __restrict__ sent_mask) {
    const int bk = blockIdx.x;          // b*K + k
    const int b = bk / Kn;

    int s = spans[2 * bk];
    int e = spans[2 * bk + 1];
    if (s < 0) s = 0; if (s > Ln) s = Ln;
    if (e < 0) e = 0; if (e > Ln) e = Ln;
    const int len = (e > s) ? (e - s) : 0;
    if (e < s) e = s;

    const int* pam = Pam + (size_t)b * (Ln + 1);
    const int msum = pam[e] - pam[s];
    const bool use_am = (msum > 0);
    const bool valid = (len > 0);

    const int d0 = threadIdx.x * 4;
    const float* xb = x + (size_t)b * Ln * Dn + d0;
    const int* amb = am + (size_t)b * Ln;
    float4 acc = {0.f, 0.f, 0.f, 0.f};

    if (!use_am) {
        // rare: no attended tokens in span -> plain mean over [s,e)
        for (int l = s; l < e; ++l)
            acc4(acc, *(const float4*)(xb + (size_t)l * Dn));
    } else {
        // interior fine-chunk range [ca, cb); edges [s,e1hi) and [e2lo,e)
        const int ca = (s + CH - 1) / CH;
        const int cb = e / CH;
        int e1hi, e2lo, e2hi;
        if (ca <= cb) { e1hi = ca * CH; e2lo = cb * CH; e2hi = e; }
        else          { e1hi = e;       e2lo = 0;       e2hi = 0; }

        // ---- prep both edge sides (VALU only) ----
        const int baseA = s,    elenA = e1hi - s;
        const int baseB = e2lo, elenB = e2hi - e2lo;
        int wvA[CH], leA[CH], anyA = 0;
        int wvB[CH], leB[CH], anyB = 0;
        if (elenA > 0) {
#pragma unroll
            for (int t = 0; t < CH; ++t) {
                const int li = (baseA + t < Ln) ? (baseA + t) : (Ln - 1);
                wvA[t] = (t < elenA) ? amb[li] : 0;
                anyA |= wvA[t];
            }
            int f = 0;
#pragma unroll
            for (int t = CH - 1; t >= 0; --t) if (wvA[t] != 0) f = t;
            int lp = f;
#pragma unroll
            for (int t = 0; t < CH; ++t) { lp = (wvA[t] != 0) ? t : lp; leA[t] = lp; }
        }
        if (elenB > 0) {
#pragma unroll
            for (int t = 0; t < CH; ++t) {
                const int li = (baseB + t < Ln) ? (baseB + t) : (Ln - 1);
                wvB[t] = (t < elenB) ? amb[li] : 0;
                anyB |= wvB[t];
            }
            int f = 0;
#pragma unroll
            for (int t = CH - 1; t >= 0; --t) if (wvB[t] != 0) f = t;
            int lp = f;
#pragma unroll
            for (int t = 0; t < CH; ++t) { lp = (wvB[t] != 0) ? t : lp; leB[t] = lp; }
        }

        // ---- issue BOTH edge load batches (in flight during interior) ----
        float4 vA[CH], vB[CH];
        if (anyA != 0) {
#pragma unroll
            for (int t = 0; t < CH; ++t)
                vA[t] = *(const float4*)(xb + (size_t)(baseA + leA[t]) * Dn);
        }
        if (anyB != 0) {
#pragma unroll
            for (int t = 0; t < CH; ++t)
                vB[t] = *(const float4*)(xb + (size_t)(baseB + leB[t]) * Dn);
        }

        // ---- interior from Pf (L2/L3-resident) ----
        if (cb > ca) {
            const float* Pb = Pf + (size_t)b * NSEG * SLOTS * Dn + d0;
            const int sa = ca / CPS, ja = ca % CPS;
            const int sb = cb / CPS, jb = cb % CPS;
            if (sa == sb) {
                float4 hi = *(const float4*)(Pb + (size_t)(sa * SLOTS + jb) * Dn);
                sub4(hi, *(const float4*)(Pb + (size_t)(sa * SLOTS + ja) * Dn));
                acc4(acc, hi);
            } else {
                float4 r = *(const float4*)(Pb + (size_t)(sa * SLOTS + CPS) * Dn);
                sub4(r, *(const float4*)(Pb + (size_t)(sa * SLOTS + ja) * Dn));
                float4 m0 = {0.f,0.f,0.f,0.f}, m1 = {0.f,0.f,0.f,0.f};
                int ss = sa + 1;
                for (; ss + 1 < sb; ss += 2) {
                    acc4(m0, *(const float4*)(Pb + (size_t)(ss * SLOTS + CPS) * Dn));
                    acc4(m1, *(const float4*)(Pb + (size_t)((ss + 1) * SLOTS + CPS) * Dn));
                }
                if (ss < sb)
                    acc4(m0, *(const float4*)(Pb + (size_t)(ss * SLOTS + CPS) * Dn));
                acc4(r, m0); acc4(r, m1);
                if (jb > 0)
                    acc4(r, *(const float4*)(Pb + (size_t)(sb * SLOTS + jb) * Dn));
                acc4(acc, r);
            }
        }

        // ---- consume edge loads ----
        if (anyA != 0) {
            float4 s0 = {0.f,0.f,0.f,0.f}, s1 = {0.f,0.f,0.f,0.f};
#pragma unroll
            for (int t = 0; t < CH; t += 2) {
                acc4w(s0, vA[t],     (float)wvA[t]);
                acc4w(s1, vA[t + 1], (float)wvA[t + 1]);
            }
            acc4(s0, s1);
            acc4(acc, s0);
        }
        if (anyB != 0) {
            float4 s0 = {0.f,0.f,0.f,0.f}, s1 = {0.f,0.f,0.f,0.f};
#pragma unroll
            for (int t = 0; t < CH; t += 2) {
                acc4w(s0, vB[t],     (float)wvB[t]);
                acc4w(s1, vB[t + 1], (float)wvB[t + 1]);
            }
            acc4(s0, s1);
            acc4(acc, s0);
        }
    }

    const float denom = use_am ? (float)msum : (float)len;
    const float inv = valid ? (1.0f / denom) : 0.0f;
    float4 outv;
    outv.x = acc.x * inv; outv.y = acc.y * inv;
    outv.z = acc.z * inv; outv.w = acc.w * inv;

    *(float4*)(H + (size_t)bk * Dn + d0) = outv;
    if (threadIdx.x == 0) sent_mask[bk] = valid ? 1.0f : 0.0f;
}

extern "C" void kernel_launch(void* const* d_in, const int* in_sizes, int n_in,
                              void* d_out, int out_size, void* d_ws, size_t ws_size,
                              hipStream_t stream) {
    const float* x = (const float*)d_in[0];
    const int* am = (const int*)d_in[1];
    const unsigned int* spans_raw = (const unsigned int*)d_in[2];

    float* H = (float*)d_out;
    float* sent_mask = H + (size_t)Bn * Kn * Dn;

    // workspace layout: dec | Pam | Pf
    const size_t dec_bytes = 8192;                                 // >= NSPAN*4
    const size_t pam_bytes = (size_t)Bn * (Ln + 1) * sizeof(int);  // 262208 B
    int* dec = (int*)d_ws;
    int* Pam = (int*)((char*)d_ws + dec_bytes);
    float* Pf = (float*)((char*)d_ws + dec_bytes + pam_bytes);     // ~18.9 MB

    fused_stage1_kernel<<<NSMALL + Bn * NSEG, 256, 0, stream>>>(
        x, am, spans_raw, Pf, Pam, dec);
    span_pool_kernel<<<Bn * Kn, 256, 0, stream>>>(
        x, am, dec, Pf, Pam, H, sent_mask);
}

// Round 14
// 40.919 us; speedup vs baseline: 1.0737x; 1.0737x over previous
//
#include <hip/hip_runtime.h>

// Problem constants (from reference): B=16, L=4096, D=1024, K=64
#define Bn 16
#define Ln 4096
#define Dn 1024
#define Kn 64
#define CH 16                  // tokens per fine chunk (slot granularity)
#define SEGTOK 128             // tokens per segment (one stream block)
#define CPS (SEGTOK / CH)      // 8 chunks per segment
#define NSEG (Ln / SEGTOK)     // 32 segments per batch row
#define SLOTS (CPS + 1)        // 9 slots: excl prefix at chunk j, slot 8 = seg total
#define NSPAN (2 * Bn * Kn)    // 2048 span ints

static __device__ __forceinline__ void acc4(float4& a, const float4 v) {
    a.x += v.x; a.y += v.y; a.z += v.z; a.w += v.w;
}
static __device__ __forceinline__ void sub4(float4& a, const float4 v) {
    a.x -= v.x; a.y -= v.y; a.z -= v.z; a.w -= v.w;
}
static __device__ __forceinline__ void acc4w(float4& a, const float4 v, float w) {
    a.x += v.x * w; a.y += v.y * w; a.z += v.z * w; a.w += v.w * w;
}

// ---------------------------------------------------------------------------
// K1 (fused stream + scan, branch-free weighted loads, am staged in LDS):
// grid = B*NSEG segment blocks + B am-prefix blocks + 1 decode block.
//  - segment blocks: the segment's 128 am values are staged in LDS ONCE,
//    so each chunk's weight reads are ds_read (lgkmcnt) instead of VMEM --
//    the effective-index chain for chunk j+1 no longer forces an in-order
//    vmcnt drain of chunk j's row loads, letting row batches overlap.
//    Per chunk: le[t] = last attended token <= t (cndmask chain), all 16
//    row loads unconditional (dups hit L1), w=0 kills dup contributions.
//  - am-prefix blocks: exclusive token prefix of attention_mask per batch.
//  - decode block: canonicalize sent_spans to int32 (int64 layout detect).
// ---------------------------------------------------------------------------
__global__ __launch_bounds__(256) void fused_stage1_kernel(
    const float* __restrict__ x, const int* __restrict__ am,
    const unsigned int* __restrict__ spans_raw,
    float* __restrict__ Pf, int* __restrict__ Pam, int* __restrict__ dec) {
    const int bc = blockIdx.x;
    __shared__ int sam[SEGTOK];          // segment am values (512 B)
    __shared__ int ssum[256];            // scan / reduce scratch

    if (bc < Bn * NSEG) {
        // ---- segment stream + intra-segment prefix ----
        const int b = bc / NSEG;
        const int seg = bc % NSEG;
        const int d0 = threadIdx.x * 4;

        const float* xp = x + ((size_t)b * Ln + (size_t)seg * SEGTOK) * Dn + d0;
        const int* amp = am + b * Ln + seg * SEGTOK;
        float* pf = Pf + (size_t)bc * SLOTS * Dn + d0;

        if (threadIdx.x < SEGTOK) sam[threadIdx.x] = amp[threadIdx.x];
        __syncthreads();

        float4 acc = {0.f, 0.f, 0.f, 0.f};
#pragma unroll
        for (int j = 0; j < CPS; ++j) {
            *(float4*)(pf + (size_t)j * Dn) = acc;   // exclusive prefix slot j

            int wv[CH];
#pragma unroll
            for (int t = 0; t < CH; ++t) wv[t] = sam[j * CH + t];  // LDS broadcast

            int any = 0;
#pragma unroll
            for (int t = 0; t < CH; ++t) any |= wv[t];

            if (any != 0) {                          // ~always taken
                int f = 0;
#pragma unroll
                for (int t = CH - 1; t >= 0; --t) if (wv[t] != 0) f = t;
                int le[CH];
                int lp = f;
#pragma unroll
                for (int t = 0; t < CH; ++t) {
                    lp = (wv[t] != 0) ? t : lp;
                    le[t] = lp;
                }
                float4 v[CH];
#pragma unroll
                for (int t = 0; t < CH; ++t)
                    v[t] = *(const float4*)(xp + (size_t)(j * CH + le[t]) * Dn);
                float4 s0 = {0.f, 0.f, 0.f, 0.f}, s1 = {0.f, 0.f, 0.f, 0.f};
#pragma unroll
                for (int t = 0; t < CH; t += 2) {
                    acc4w(s0, v[t],     (float)wv[t]);
                    acc4w(s1, v[t + 1], (float)wv[t + 1]);
                }
                acc4(s0, s1);
                acc4(acc, s0);
            }
        }
        *(float4*)(pf + (size_t)CPS * Dn) = acc;     // segment total
    } else if (bc < Bn * NSEG + Bn) {
        // ---- am token-prefix for batch b ----
        const int b = bc - Bn * NSEG;
        const int t = threadIdx.x;
        const int i0 = t * 16;
        const int* amb = am + (size_t)b * Ln;
        int loc[16];
        int lsum = 0;
#pragma unroll
        for (int j = 0; j < 16; ++j) { loc[j] = amb[i0 + j]; lsum += loc[j]; }

        ssum[t] = lsum;
        __syncthreads();
        for (int off = 1; off < 256; off <<= 1) {
            int v2 = (t >= off) ? ssum[t - off] : 0;
            __syncthreads();
            ssum[t] += v2;
            __syncthreads();
        }
        int run = ssum[t] - lsum;                    // exclusive offset
        int* pam = Pam + (size_t)b * (Ln + 1);
#pragma unroll
        for (int j = 0; j < 16; ++j) { pam[i0 + j] = run; run += loc[j]; }
        if (t == 255) pam[Ln] = run;
    } else {
        // ---- span decode ----
        unsigned int acc = 0;
        for (int i = threadIdx.x; i < NSPAN / 2; i += 256)
            acc |= spans_raw[2 * i + 1];
        ssum[threadIdx.x] = (int)acc;
        __syncthreads();
        for (int off = 128; off > 0; off >>= 1) {
            if ((int)threadIdx.x < off) ssum[threadIdx.x] |= ssum[threadIdx.x + off];
            __syncthreads();
        }
        const bool is64 = (ssum[0] == 0);
        for (int i = threadIdx.x; i < NSPAN; i += 256)
            dec[i] = is64 ? (int)spans_raw[2 * i] : (int)spans_raw[i];
    }
}

// ---------------------------------------------------------------------------
// K2: per-span pooling (R11 form). grid = B*K blocks, 256 threads.
// mask_sum = Pam[e]-Pam[s]. use_am interior: intra-seg prefix diffs +
// middle segment totals. Edge token ranges use the branch-free
// effective-index pattern, sides processed sequentially (low VGPR).
// ---------------------------------------------------------------------------
__global__ __launch_bounds__(256) void span_pool_kernel(
    const float* __restrict__ x, const int* __restrict__ am,
    const int* __restrict__ spans, const float* __restrict__ Pf,
    const int* __restrict__ Pam, float* __restrict__ H,
    float* __restrict__ sent_mask) {
    const int bk = blockIdx.x;          // b*K + k
    const int b = bk / Kn;

    int s = spans[2 * bk];
    int e = spans[2 * bk + 1];
    if (s < 0) s = 0; if (s > Ln) s = Ln;
    if (e < 0) e = 0; if (e > Ln) e = Ln;
    const int len = (e > s) ? (e - s) : 0;
    if (e < s) e = s;

    const int* pam = Pam + (size_t)b * (Ln + 1);
    const int msum = pam[e] - pam[s];
    const bool use_am = (msum > 0);
    const bool valid = (len > 0);

    const int d0 = threadIdx.x * 4;
    const float* xb = x + (size_t)b * Ln * Dn + d0;
    const int* amb = am + (size_t)b * Ln;
    float4 acc = {0.f, 0.f, 0.f, 0.f};

    if (!use_am) {
        // rare: no attended tokens in span -> plain mean over [s,e)
        for (int l = s; l < e; ++l)
            acc4(acc, *(const float4*)(xb + (size_t)l * Dn));
    } else {
        // interior fine-chunk range [ca, cb); edges [s,e1hi) and [e2lo,e)
        const int ca = (s + CH - 1) / CH;
        const int cb = e / CH;
        int e1hi, e2lo, e2hi;
        if (ca <= cb) { e1hi = ca * CH; e2lo = cb * CH; e2hi = e; }
        else          { e1hi = e;       e2lo = 0;       e2hi = 0; }

        if (cb > ca) {
            const float* Pb = Pf + (size_t)b * NSEG * SLOTS * Dn + d0;
            const int sa = ca / CPS, ja = ca % CPS;
            const int sb = cb / CPS, jb = cb % CPS;
            if (sa == sb) {
                acc = *(const float4*)(Pb + (size_t)(sa * SLOTS + jb) * Dn);
                sub4(acc, *(const float4*)(Pb + (size_t)(sa * SLOTS + ja) * Dn));
            } else {
                acc = *(const float4*)(Pb + (size_t)(sa * SLOTS + CPS) * Dn);
                sub4(acc, *(const float4*)(Pb + (size_t)(sa * SLOTS + ja) * Dn));
                float4 m0 = {0.f,0.f,0.f,0.f}, m1 = {0.f,0.f,0.f,0.f};
                int ss = sa + 1;
                for (; ss + 1 < sb; ss += 2) {
                    acc4(m0, *(const float4*)(Pb + (size_t)(ss * SLOTS + CPS) * Dn));
                    acc4(m1, *(const float4*)(Pb + (size_t)((ss + 1) * SLOTS + CPS) * Dn));
                }
                if (ss < sb)
                    acc4(m0, *(const float4*)(Pb + (size_t)(ss * SLOTS + CPS) * Dn));
                acc4(acc, m0); acc4(acc, m1);
                if (jb > 0)
                    acc4(acc, *(const float4*)(Pb + (size_t)(sb * SLOTS + jb) * Dn));
            }
        }

        // ---- branch-free edge sides (base, elen < 16 each) ----
#pragma unroll
        for (int side = 0; side < 2; ++side) {
            const int base = side ? e2lo : s;
            const int elen = side ? (e2hi - e2lo) : (e1hi - s);
            if (elen > 0) {
                int wv[CH];
#pragma unroll
                for (int t = 0; t < CH; ++t) {
                    const int li = (base + t < Ln) ? (base + t) : (Ln - 1);
                    wv[t] = (t < elen) ? amb[li] : 0;
                }
                int any = 0;
#pragma unroll
                for (int t = 0; t < CH; ++t) any |= wv[t];
                if (any != 0) {
                    int f = 0;
#pragma unroll
                    for (int t = CH - 1; t >= 0; --t) if (wv[t] != 0) f = t;
                    int le[CH];
                    int lp = f;
#pragma unroll
                    for (int t = 0; t < CH; ++t) {
                        lp = (wv[t] != 0) ? t : lp;
                        le[t] = lp;
                    }
                    float4 v[CH];
#pragma unroll
                    for (int t = 0; t < CH; ++t)
                        v[t] = *(const float4*)(xb + (size_t)(base + le[t]) * Dn);
                    float4 s0 = {0.f,0.f,0.f,0.f}, s1 = {0.f,0.f,0.f,0.f};
#pragma unroll
                    for (int t = 0; t < CH; t += 2) {
                        acc4w(s0, v[t],     (float)wv[t]);
                        acc4w(s1, v[t + 1], (float)wv[t + 1]);
                    }
                    acc4(s0, s1);
                    acc4(acc, s0);
                }
            }
        }
    }

    const float denom = use_am ? (float)msum : (float)len;
    const float inv = valid ? (1.0f / denom) : 0.0f;
    float4 outv;
    outv.x = acc.x * inv; outv.y = acc.y * inv;
    outv.z = acc.z * inv; outv.w = acc.w * inv;

    *(float4*)(H + (size_t)bk * Dn + d0) = outv;
    if (threadIdx.x == 0) sent_mask[bk] = valid ? 1.0f : 0.0f;
}

extern "C" void kernel_launch(void* const* d_in, const int* in_sizes, int n_in,
                              void* d_out, int out_size, void* d_ws, size_t ws_size,
                              hipStream_t stream) {
    const float* x = (const float*)d_in[0];
    const int* am = (const int*)d_in[1];
    const unsigned int* spans_raw = (const unsigned int*)d_in[2];

    float* H = (float*)d_out;
    float* sent_mask = H + (size_t)Bn * Kn * Dn;

    // workspace layout: dec | Pam | Pf
    const size_t dec_bytes = 8192;                                 // >= NSPAN*4
    const size_t pam_bytes = (size_t)Bn * (Ln + 1) * sizeof(int);  // 262208 B
    int* dec = (int*)d_ws;
    int* Pam = (int*)((char*)d_ws + dec_bytes);
    float* Pf = (float*)((char*)d_ws + dec_bytes + pam_bytes);     // ~18.9 MB

    fused_stage1_kernel<<<Bn * NSEG + Bn + 1, 256, 0, stream>>>(
        x, am, spans_raw, Pf, Pam, dec);
    span_pool_kernel<<<Bn * Kn, 256, 0, stream>>>(
        x, am, dec, Pf, Pam, H, sent_mask);
}

// Round 15
// 38.660 us; speedup vs baseline: 1.1364x; 1.0584x over previous
//
#include <hip/hip_runtime.h>

// Problem constants (from reference): B=16, L=4096, D=1024, K=64
#define Bn 16
#define Ln 4096
#define Dn 1024
#define Kn 64
#define CH 16                  // tokens per fine chunk (slot granularity)
#define SEGTOK 128             // tokens per segment (one stream block)
#define CPS (SEGTOK / CH)      // 8 chunks per segment
#define NSEG (Ln / SEGTOK)     // 32 segments per batch row
#define SLOTS (CPS + 1)        // 9 slots: excl prefix at chunk j, slot 8 = seg total
#define NSPAN (2 * Bn * Kn)    // 2048 span ints

static __device__ __forceinline__ void acc4(float4& a, const float4 v) {
    a.x += v.x; a.y += v.y; a.z += v.z; a.w += v.w;
}
static __device__ __forceinline__ void sub4(float4& a, const float4 v) {
    a.x -= v.x; a.y -= v.y; a.z -= v.z; a.w -= v.w;
}
static __device__ __forceinline__ void acc4w(float4& a, const float4 v, float w) {
    a.x += v.x * w; a.y += v.y * w; a.z += v.z * w; a.w += v.w * w;
}

// 8-slot branch-free weighted edge: acc += sign * sum_{t<n, am!=0} w_t x[base+t]
static __device__ __forceinline__ void edge8(
    const float* __restrict__ xb, const int* __restrict__ amb,
    int base, int n, float sign, float4& acc) {
    int wv[8];
    int any = 0;
#pragma unroll
    for (int t = 0; t < 8; ++t) {
        const int li = (base + t < Ln) ? (base + t) : (Ln - 1);
        wv[t] = (t < n) ? amb[li] : 0;
        any |= wv[t];
    }
    if (any != 0) {
        int f = 0;
#pragma unroll
        for (int t = 7; t >= 0; --t) if (wv[t] != 0) f = t;
        int le[8];
        int lp = f;
#pragma unroll
        for (int t = 0; t < 8; ++t) { lp = (wv[t] != 0) ? t : lp; le[t] = lp; }
        float4 v[8];
#pragma unroll
        for (int t = 0; t < 8; ++t)
            v[t] = *(const float4*)(xb + (size_t)(base + le[t]) * Dn);
        float4 s0 = {0.f,0.f,0.f,0.f}, s1 = {0.f,0.f,0.f,0.f};
#pragma unroll
        for (int t = 0; t < 8; t += 2) {
            acc4w(s0, v[t],     sign * (float)wv[t]);
            acc4w(s1, v[t + 1], sign * (float)wv[t + 1]);
        }
        acc4(s0, s1);
        acc4(acc, s0);
    }
}

// ---------------------------------------------------------------------------
// K1 (fused stream + scan, branch-free weighted loads) — identical to the
// 40.2us R12 version. Per 16-token chunk: effective index le[t] = last
// attended token <= t (cndmask chain); all 16 row loads unconditional
// (duplicates hit L1), w=0 kills duplicate contributions exactly.
// ---------------------------------------------------------------------------
__global__ __launch_bounds__(256) void fused_stage1_kernel(
    const float* __restrict__ x, const int* __restrict__ am,
    const unsigned int* __restrict__ spans_raw,
    float* __restrict__ Pf, int* __restrict__ Pam, int* __restrict__ dec) {
    const int bc = blockIdx.x;

    if (bc < Bn * NSEG) {
        const int b = bc / NSEG;
        const int seg = bc % NSEG;
        const int d0 = threadIdx.x * 4;

        const float* xp = x + ((size_t)b * Ln + (size_t)seg * SEGTOK) * Dn + d0;
        const int* amp = am + b * Ln + seg * SEGTOK;
        float* pf = Pf + (size_t)bc * SLOTS * Dn + d0;

        float4 acc = {0.f, 0.f, 0.f, 0.f};
#pragma unroll
        for (int j = 0; j < CPS; ++j) {
            *(float4*)(pf + (size_t)j * Dn) = acc;   // exclusive prefix slot j

            int wv[CH];
#pragma unroll
            for (int t = 0; t < CH; ++t) wv[t] = amp[j * CH + t];

            int any = 0;
#pragma unroll
            for (int t = 0; t < CH; ++t) any |= wv[t];

            if (any != 0) {                          // ~always taken
                int f = 0;
#pragma unroll
                for (int t = CH - 1; t >= 0; --t) if (wv[t] != 0) f = t;
                int le[CH];
                int lp = f;
#pragma unroll
                for (int t = 0; t < CH; ++t) {
                    lp = (wv[t] != 0) ? t : lp;
                    le[t] = lp;
                }
                float4 v[CH];
#pragma unroll
                for (int t = 0; t < CH; ++t)
                    v[t] = *(const float4*)(xp + (size_t)(j * CH + le[t]) * Dn);
                float4 s0 = {0.f, 0.f, 0.f, 0.f}, s1 = {0.f, 0.f, 0.f, 0.f};
#pragma unroll
                for (int t = 0; t < CH; t += 2) {
                    acc4w(s0, v[t],     (float)wv[t]);
                    acc4w(s1, v[t + 1], (float)wv[t + 1]);
                }
                acc4(s0, s1);
                acc4(acc, s0);
            }
        }
        *(float4*)(pf + (size_t)CPS * Dn) = acc;     // segment total
    } else if (bc < Bn * NSEG + Bn) {
        // ---- am token-prefix for batch b ----
        const int b = bc - Bn * NSEG;
        const int t = threadIdx.x;
        const int i0 = t * 16;
        const int* amb = am + (size_t)b * Ln;
        int loc[16];
        int lsum = 0;
#pragma unroll
        for (int j = 0; j < 16; ++j) { loc[j] = amb[i0 + j]; lsum += loc[j]; }

        __shared__ int ssum[256];
        ssum[t] = lsum;
        __syncthreads();
        for (int off = 1; off < 256; off <<= 1) {
            int v2 = (t >= off) ? ssum[t - off] : 0;
            __syncthreads();
            ssum[t] += v2;
            __syncthreads();
        }
        int run = ssum[t] - lsum;                    // exclusive offset
        int* pam = Pam + (size_t)b * (Ln + 1);
#pragma unroll
        for (int j = 0; j < 16; ++j) { pam[i0 + j] = run; run += loc[j]; }
        if (t == 255) pam[Ln] = run;
    } else {
        // ---- span decode ----
        __shared__ unsigned int sred[256];
        unsigned int acc = 0;
        for (int i = threadIdx.x; i < NSPAN / 2; i += 256)
            acc |= spans_raw[2 * i + 1];
        sred[threadIdx.x] = acc;
        __syncthreads();
        for (int off = 128; off > 0; off >>= 1) {
            if ((int)threadIdx.x < off) sred[threadIdx.x] |= sred[threadIdx.x + off];
            __syncthreads();
        }
        const bool is64 = (sred[0] == 0u);
        for (int i = threadIdx.x; i < NSPAN; i += 256)
            dec[i] = is64 ? (int)spans_raw[2 * i] : (int)spans_raw[i];
    }
}

// ---------------------------------------------------------------------------
// K2: per-span pooling with COMPLEMENT edges. grid = B*K blocks.
// mask_sum = Pam[e]-Pam[s]. Interior = slot diffs + middle segment totals.
// Edge side (within one 16-chunk): cost min(elen, 16-elen) <= 8 rows --
// direct sum, or full-chunk slot-diff minus complement (sign=-1).
// Span-inside-one-chunk (rare): 16-slot direct path.
// ---------------------------------------------------------------------------
__global__ __launch_bounds__(256) void span_pool_kernel(
    const float* __restrict__ x, const int* __restrict__ am,
    const int* __restrict__ spans, const float* __restrict__ Pf,
    const int* __restrict__ Pam, float* __restrict__ H,
    float* __restrict__ sent_mask) {
    const int bk = blockIdx.x;          // b*K + k
    const int b = bk / Kn;

    int s = spans[2 * bk];
    int e = spans[2 * bk + 1];
    if (s < 0) s = 0; if (s > Ln) s = Ln;
    if (e < 0) e = 0; if (e > Ln) e = Ln;
    const int len = (e > s) ? (e - s) : 0;
    if (e < s) e = s;

    const int* pam = Pam + (size_t)b * (Ln + 1);
    const int msum = pam[e] - pam[s];
    const bool use_am = (msum > 0);
    const bool valid = (len > 0);

    const int d0 = threadIdx.x * 4;
    const float* xb = x + (size_t)b * Ln * Dn + d0;
    const int* amb = am + (size_t)b * Ln;
    float4 acc = {0.f, 0.f, 0.f, 0.f};

    if (!use_am) {
        // rare: no attended tokens in span -> plain mean over [s,e)
        for (int l = s; l < e; ++l)
            acc4(acc, *(const float4*)(xb + (size_t)l * Dn));
    } else {
        const int ca = (s + CH - 1) / CH;
        const int cb = e / CH;
        const float* Pb = Pf + (size_t)b * NSEG * SLOTS * Dn + d0;

        if (ca <= cb) {
            // ---- interior [ca*CH, cb*CH) from prefix slots ----
            if (cb > ca) {
                const int sa = ca / CPS, ja = ca % CPS;
                const int sb = cb / CPS, jb = cb % CPS;
                if (sa == sb) {
                    float4 r = *(const float4*)(Pb + (size_t)(sa * SLOTS + jb) * Dn);
                    sub4(r, *(const float4*)(Pb + (size_t)(sa * SLOTS + ja) * Dn));
                    acc4(acc, r);
                } else {
                    float4 r = *(const float4*)(Pb + (size_t)(sa * SLOTS + CPS) * Dn);
                    sub4(r, *(const float4*)(Pb + (size_t)(sa * SLOTS + ja) * Dn));
                    float4 m0 = {0.f,0.f,0.f,0.f}, m1 = {0.f,0.f,0.f,0.f};
                    int ss = sa + 1;
                    for (; ss + 1 < sb; ss += 2) {
                        acc4(m0, *(const float4*)(Pb + (size_t)(ss * SLOTS + CPS) * Dn));
                        acc4(m1, *(const float4*)(Pb + (size_t)((ss + 1) * SLOTS + CPS) * Dn));
                    }
                    if (ss < sb)
                        acc4(m0, *(const float4*)(Pb + (size_t)(ss * SLOTS + CPS) * Dn));
                    acc4(r, m0); acc4(r, m1);
                    if (jb > 0)
                        acc4(r, *(const float4*)(Pb + (size_t)(sb * SLOTS + jb) * Dn));
                    acc4(acc, r);
                }
            }

            // ---- side A: [s, ca*CH), elenA in [0,15] ----
            const int elenA = ca * CH - s;
            if (elenA > 0) {
                if (elenA <= 8) {
                    edge8(xb, amb, s, elenA, 1.f, acc);
                } else {
                    const int g = ca - 1;
                    const int sg = g / CPS, j = g % CPS;
                    acc4(acc, *(const float4*)(Pb + (size_t)(sg * SLOTS + j + 1) * Dn));
                    sub4(acc, *(const float4*)(Pb + (size_t)(sg * SLOTS + j) * Dn));
                    edge8(xb, amb, g * CH, CH - elenA, -1.f, acc);
                }
            }

            // ---- side B: [cb*CH, e), elenB in [0,15] ----
            const int elenB = e - cb * CH;
            if (elenB > 0) {
                if (elenB <= 8) {
                    edge8(xb, amb, cb * CH, elenB, 1.f, acc);
                } else {
                    const int g = cb;
                    const int sg = g / CPS, j = g % CPS;
                    acc4(acc, *(const float4*)(Pb + (size_t)(sg * SLOTS + j + 1) * Dn));
                    sub4(acc, *(const float4*)(Pb + (size_t)(sg * SLOTS + j) * Dn));
                    edge8(xb, amb, e, CH - elenB, -1.f, acc);
                }
            }
        } else {
            // span strictly inside one chunk (len <= 15): 16-slot direct
            int wv[CH];
#pragma unroll
            for (int t = 0; t < CH; ++t) {
                const int li = (s + t < Ln) ? (s + t) : (Ln - 1);
                wv[t] = (t < len) ? amb[li] : 0;
            }
            int any = 0;
#pragma unroll
            for (int t = 0; t < CH; ++t) any |= wv[t];
            if (any != 0) {
                int f = 0;
#pragma unroll
                for (int t = CH - 1; t >= 0; --t) if (wv[t] != 0) f = t;
                int le[CH];
                int lp = f;
#pragma unroll
                for (int t = 0; t < CH; ++t) {
                    lp = (wv[t] != 0) ? t : lp;
                    le[t] = lp;
                }
                float4 v[CH];
#pragma unroll
                for (int t = 0; t < CH; ++t)
                    v[t] = *(const float4*)(xb + (size_t)(s + le[t]) * Dn);
                float4 s0 = {0.f,0.f,0.f,0.f}, s1 = {0.f,0.f,0.f,0.f};
#pragma unroll
                for (int t = 0; t < CH; t += 2) {
                    acc4w(s0, v[t],     (float)wv[t]);
                    acc4w(s1, v[t + 1], (float)wv[t + 1]);
                }
                acc4(s0, s1);
                acc4(acc, s0);
            }
        }
    }

    const float denom = use_am ? (float)msum : (float)len;
    const float inv = valid ? (1.0f / denom) : 0.0f;
    float4 outv;
    outv.x = acc.x * inv; outv.y = acc.y * inv;
    outv.z = acc.z * inv; outv.w = acc.w * inv;

    *(float4*)(H + (size_t)bk * Dn + d0) = outv;
    if (threadIdx.x == 0) sent_mask[bk] = valid ? 1.0f : 0.0f;
}

extern "C" void kernel_launch(void* const* d_in, const int* in_sizes, int n_in,
                              void* d_out, int out_size, void* d_ws, size_t ws_size,
                              hipStream_t stream) {
    const float* x = (const float*)d_in[0];
    const int* am = (const int*)d_in[1];
    const unsigned int* spans_raw = (const unsigned int*)d_in[2];

    float* H = (float*)d_out;
    float* sent_mask = H + (size_t)Bn * Kn * Dn;

    // workspace layout: dec | Pam | Pf
    const size_t dec_bytes = 8192;                                 // >= NSPAN*4
    const size_t pam_bytes = (size_t)Bn * (Ln + 1) * sizeof(int);  // 262208 B
    int* dec = (int*)d_ws;
    int* Pam = (int*)((char*)d_ws + dec_bytes);
    float* Pf = (float*)((char*)d_ws + dec_bytes + pam_bytes);     // ~18.9 MB

    fused_stage1_kernel<<<Bn * NSEG + Bn + 1, 256, 0, stream>>>(
        x, am, spans_raw, Pf, Pam, dec);
    span_pool_kernel<<<Bn * Kn, 256, 0, stream>>>(
        x, am, dec, Pf, Pam, H, sent_mask);
}

// Round 16
// 37.716 us; speedup vs baseline: 1.1649x; 1.0250x over previous
//
#include <hip/hip_runtime.h>

// Problem constants (from reference): B=16, L=4096, D=1024, K=64
#define Bn 16
#define Ln 4096
#define Dn 1024
#define Kn 64
#define CH 16                  // tokens per fine chunk (slot granularity)
#define SEGTOK 128             // tokens per segment (one stream block)
#define CPS (SEGTOK / CH)      // 8 chunks per segment
#define NSEG (Ln / SEGTOK)     // 32 segments per batch row
#define SLOTS (CPS + 1)        // 9 slots: excl prefix at chunk j, slot 8 = seg total
#define NSPAN (2 * Bn * Kn)    // 2048 span ints
#define QBLK 4                 // K2: d-quarters per span (one wave each)

static __device__ __forceinline__ void acc4(float4& a, const float4 v) {
    a.x += v.x; a.y += v.y; a.z += v.z; a.w += v.w;
}
static __device__ __forceinline__ void sub4(float4& a, const float4 v) {
    a.x -= v.x; a.y -= v.y; a.z -= v.z; a.w -= v.w;
}
static __device__ __forceinline__ void acc4w(float4& a, const float4 v, float w) {
    a.x += v.x * w; a.y += v.y * w; a.z += v.z * w; a.w += v.w * w;
}

// 8-slot branch-free weighted edge: acc += sign * sum_{t<n, am!=0} w_t x[base+t]
static __device__ __forceinline__ void edge8(
    const float* __restrict__ xb, const int* __restrict__ amb,
    int base, int n, float sign, float4& acc) {
    int wv[8];
    int any = 0;
#pragma unroll
    for (int t = 0; t < 8; ++t) {
        const int li = (base + t < Ln) ? (base + t) : (Ln - 1);
        wv[t] = (t < n) ? amb[li] : 0;
        any |= wv[t];
    }
    if (any != 0) {
        int f = 0;
#pragma unroll
        for (int t = 7; t >= 0; --t) if (wv[t] != 0) f = t;
        int le[8];
        int lp = f;
#pragma unroll
        for (int t = 0; t < 8; ++t) { lp = (wv[t] != 0) ? t : lp; le[t] = lp; }
        float4 v[8];
#pragma unroll
        for (int t = 0; t < 8; ++t)
            v[t] = *(const float4*)(xb + (size_t)(base + le[t]) * Dn);
        float4 s0 = {0.f,0.f,0.f,0.f}, s1 = {0.f,0.f,0.f,0.f};
#pragma unroll
        for (int t = 0; t < 8; t += 2) {
            acc4w(s0, v[t],     sign * (float)wv[t]);
            acc4w(s1, v[t + 1], sign * (float)wv[t + 1]);
        }
        acc4(s0, s1);
        acc4(acc, s0);
    }
}

// ---------------------------------------------------------------------------
// K1 (fused stream + scan, branch-free weighted loads) — identical to R15.
// ---------------------------------------------------------------------------
__global__ __launch_bounds__(256) void fused_stage1_kernel(
    const float* __restrict__ x, const int* __restrict__ am,
    const unsigned int* __restrict__ spans_raw,
    float* __restrict__ Pf, int* __restrict__ Pam, int* __restrict__ dec) {
    const int bc = blockIdx.x;

    if (bc < Bn * NSEG) {
        const int b = bc / NSEG;
        const int seg = bc % NSEG;
        const int d0 = threadIdx.x * 4;

        const float* xp = x + ((size_t)b * Ln + (size_t)seg * SEGTOK) * Dn + d0;
        const int* amp = am + b * Ln + seg * SEGTOK;
        float* pf = Pf + (size_t)bc * SLOTS * Dn + d0;

        float4 acc = {0.f, 0.f, 0.f, 0.f};
#pragma unroll
        for (int j = 0; j < CPS; ++j) {
            *(float4*)(pf + (size_t)j * Dn) = acc;   // exclusive prefix slot j

            int wv[CH];
#pragma unroll
            for (int t = 0; t < CH; ++t) wv[t] = amp[j * CH + t];

            int any = 0;
#pragma unroll
            for (int t = 0; t < CH; ++t) any |= wv[t];

            if (any != 0) {                          // ~always taken
                int f = 0;
#pragma unroll
                for (int t = CH - 1; t >= 0; --t) if (wv[t] != 0) f = t;
                int le[CH];
                int lp = f;
#pragma unroll
                for (int t = 0; t < CH; ++t) {
                    lp = (wv[t] != 0) ? t : lp;
                    le[t] = lp;
                }
                float4 v[CH];
#pragma unroll
                for (int t = 0; t < CH; ++t)
                    v[t] = *(const float4*)(xp + (size_t)(j * CH + le[t]) * Dn);
                float4 s0 = {0.f, 0.f, 0.f, 0.f}, s1 = {0.f, 0.f, 0.f, 0.f};
#pragma unroll
                for (int t = 0; t < CH; t += 2) {
                    acc4w(s0, v[t],     (float)wv[t]);
                    acc4w(s1, v[t + 1], (float)wv[t + 1]);
                }
                acc4(s0, s1);
                acc4(acc, s0);
            }
        }
        *(float4*)(pf + (size_t)CPS * Dn) = acc;     // segment total
    } else if (bc < Bn * NSEG + Bn) {
        // ---- am token-prefix for batch b ----
        const int b = bc - Bn * NSEG;
        const int t = threadIdx.x;
        const int i0 = t * 16;
        const int* amb = am + (size_t)b * Ln;
        int loc[16];
        int lsum = 0;
#pragma unroll
        for (int j = 0; j < 16; ++j) { loc[j] = amb[i0 + j]; lsum += loc[j]; }

        __shared__ int ssum[256];
        ssum[t] = lsum;
        __syncthreads();
        for (int off = 1; off < 256; off <<= 1) {
            int v2 = (t >= off) ? ssum[t - off] : 0;
            __syncthreads();
            ssum[t] += v2;
            __syncthreads();
        }
        int run = ssum[t] - lsum;                    // exclusive offset
        int* pam = Pam + (size_t)b * (Ln + 1);
#pragma unroll
        for (int j = 0; j < 16; ++j) { pam[i0 + j] = run; run += loc[j]; }
        if (t == 255) pam[Ln] = run;
    } else {
        // ---- span decode ----
        __shared__ unsigned int sred[256];
        unsigned int acc = 0;
        for (int i = threadIdx.x; i < NSPAN / 2; i += 256)
            acc |= spans_raw[2 * i + 1];
        sred[threadIdx.x] = acc;
        __syncthreads();
        for (int off = 128; off > 0; off >>= 1) {
            if ((int)threadIdx.x < off) sred[threadIdx.x] |= sred[threadIdx.x + off];
            __syncthreads();
        }
        const bool is64 = (sred[0] == 0u);
        for (int i = threadIdx.x; i < NSPAN; i += 256)
            dec[i] = is64 ? (int)spans_raw[2 * i] : (int)spans_raw[i];
    }
}

// ---------------------------------------------------------------------------
// K2: per-span pooling, ONE WAVE PER D-QUARTER. grid = B*K*QBLK blocks of
// 64 threads (16 independent blocks/CU -> latency chains overlap 16-deep).
// Same complement-edge algorithm as R15; quarter q covers d in
// [q*256, q*256+256). sent_mask written by quarter 0.
// ---------------------------------------------------------------------------
__global__ __launch_bounds__(64) void span_pool_kernel(
    const float* __restrict__ x, const int* __restrict__ am,
    const int* __restrict__ spans, const float* __restrict__ Pf,
    const int* __restrict__ Pam, float* __restrict__ H,
    float* __restrict__ sent_mask) {
    const int gb = blockIdx.x;
    const int bk = gb >> 2;             // span id: b*K + k
    const int q  = gb & 3;              // d-quarter
    const int b = bk / Kn;

    int s = spans[2 * bk];
    int e = spans[2 * bk + 1];
    if (s < 0) s = 0; if (s > Ln) s = Ln;
    if (e < 0) e = 0; if (e > Ln) e = Ln;
    const int len = (e > s) ? (e - s) : 0;
    if (e < s) e = s;

    const int* pam = Pam + (size_t)b * (Ln + 1);
    const int msum = pam[e] - pam[s];
    const bool use_am = (msum > 0);
    const bool valid = (len > 0);

    const int d0 = q * 256 + (int)threadIdx.x * 4;
    const float* xb = x + (size_t)b * Ln * Dn + d0;
    const int* amb = am + (size_t)b * Ln;
    float4 acc = {0.f, 0.f, 0.f, 0.f};

    if (!use_am) {
        // rare: no attended tokens in span -> plain mean over [s,e)
        for (int l = s; l < e; ++l)
            acc4(acc, *(const float4*)(xb + (size_t)l * Dn));
    } else {
        const int ca = (s + CH - 1) / CH;
        const int cb = e / CH;
        const float* Pb = Pf + (size_t)b * NSEG * SLOTS * Dn + d0;

        if (ca <= cb) {
            // ---- interior [ca*CH, cb*CH) from prefix slots ----
            if (cb > ca) {
                const int sa = ca / CPS, ja = ca % CPS;
                const int sb = cb / CPS, jb = cb % CPS;
                if (sa == sb) {
                    float4 r = *(const float4*)(Pb + (size_t)(sa * SLOTS + jb) * Dn);
                    sub4(r, *(const float4*)(Pb + (size_t)(sa * SLOTS + ja) * Dn));
                    acc4(acc, r);
                } else {
                    float4 r = *(const float4*)(Pb + (size_t)(sa * SLOTS + CPS) * Dn);
                    sub4(r, *(const float4*)(Pb + (size_t)(sa * SLOTS + ja) * Dn));
                    float4 m0 = {0.f,0.f,0.f,0.f}, m1 = {0.f,0.f,0.f,0.f};
                    int ss = sa + 1;
                    for (; ss + 1 < sb; ss += 2) {
                        acc4(m0, *(const float4*)(Pb + (size_t)(ss * SLOTS + CPS) * Dn));
                        acc4(m1, *(const float4*)(Pb + (size_t)((ss + 1) * SLOTS + CPS) * Dn));
                    }
                    if (ss < sb)
                        acc4(m0, *(const float4*)(Pb + (size_t)(ss * SLOTS + CPS) * Dn));
                    acc4(r, m0); acc4(r, m1);
                    if (jb > 0)
                        acc4(r, *(const float4*)(Pb + (size_t)(sb * SLOTS + jb) * Dn));
                    acc4(acc, r);
                }
            }

            // ---- side A: [s, ca*CH), elenA in [0,15] ----
            const int elenA = ca * CH - s;
            if (elenA > 0) {
                if (elenA <= 8) {
                    edge8(xb, amb, s, elenA, 1.f, acc);
                } else {
                    const int g = ca - 1;
                    const int sg = g / CPS, j = g % CPS;
                    acc4(acc, *(const float4*)(Pb + (size_t)(sg * SLOTS + j + 1) * Dn));
                    sub4(acc, *(const float4*)(Pb + (size_t)(sg * SLOTS + j) * Dn));
                    edge8(xb, amb, g * CH, CH - elenA, -1.f, acc);
                }
            }

            // ---- side B: [cb*CH, e), elenB in [0,15] ----
            const int elenB = e - cb * CH;
            if (elenB > 0) {
                if (elenB <= 8) {
                    edge8(xb, amb, cb * CH, elenB, 1.f, acc);
                } else {
                    const int g = cb;
                    const int sg = g / CPS, j = g % CPS;
                    acc4(acc, *(const float4*)(Pb + (size_t)(sg * SLOTS + j + 1) * Dn));
                    sub4(acc, *(const float4*)(Pb + (size_t)(sg * SLOTS + j) * Dn));
                    edge8(xb, amb, e, CH - elenB, -1.f, acc);
                }
            }
        } else {
            // span strictly inside one chunk (len <= 15): 16-slot direct
            int wv[CH];
#pragma unroll
            for (int t = 0; t < CH; ++t) {
                const int li = (s + t < Ln) ? (s + t) : (Ln - 1);
                wv[t] = (t < len) ? amb[li] : 0;
            }
            int any = 0;
#pragma unroll
            for (int t = 0; t < CH; ++t) any |= wv[t];
            if (any != 0) {
                int f = 0;
#pragma unroll
                for (int t = CH - 1; t >= 0; --t) if (wv[t] != 0) f = t;
                int le[CH];
                int lp = f;
#pragma unroll
                for (int t = 0; t < CH; ++t) {
                    lp = (wv[t] != 0) ? t : lp;
                    le[t] = lp;
                }
                float4 v[CH];
#pragma unroll
                for (int t = 0; t < CH; ++t)
                    v[t] = *(const float4*)(xb + (size_t)(s + le[t]) * Dn);
                float4 s0 = {0.f,0.f,0.f,0.f}, s1 = {0.f,0.f,0.f,0.f};
#pragma unroll
                for (int t = 0; t < CH; t += 2) {
                    acc4w(s0, v[t],     (float)wv[t]);
                    acc4w(s1, v[t + 1], (float)wv[t + 1]);
                }
                acc4(s0, s1);
                acc4(acc, s0);
            }
        }
    }

    const float denom = use_am ? (float)msum : (float)len;
    const float inv = valid ? (1.0f / denom) : 0.0f;
    float4 outv;
    outv.x = acc.x * inv; outv.y = acc.y * inv;
    outv.z = acc.z * inv; outv.w = acc.w * inv;

    *(float4*)(H + (size_t)bk * Dn + d0) = outv;
    if (threadIdx.x == 0 && q == 0) sent_mask[bk] = valid ? 1.0f : 0.0f;
}

extern "C" void kernel_launch(void* const* d_in, const int* in_sizes, int n_in,
                              void* d_out, int out_size, void* d_ws, size_t ws_size,
                              hipStream_t stream) {
    const float* x = (const float*)d_in[0];
    const int* am = (const int*)d_in[1];
    const unsigned int* spans_raw = (const unsigned int*)d_in[2];

    float* H = (float*)d_out;
    float* sent_mask = H + (size_t)Bn * Kn * Dn;

    // workspace layout: dec | Pam | Pf
    const size_t dec_bytes = 8192;                                 // >= NSPAN*4
    const size_t pam_bytes = (size_t)Bn * (Ln + 1) * sizeof(int);  // 262208 B
    int* dec = (int*)d_ws;
    int* Pam = (int*)((char*)d_ws + dec_bytes);
    float* Pf = (float*)((char*)d_ws + dec_bytes + pam_bytes);     // ~18.9 MB

    fused_stage1_kernel<<<Bn * NSEG + Bn + 1, 256, 0, stream>>>(
        x, am, spans_raw, Pf, Pam, dec);
    span_pool_kernel<<<Bn * Kn * QBLK, 64, 0, stream>>>(
        x, am, dec, Pf, Pam, H, sent_mask);
}

// Round 17
// 37.642 us; speedup vs baseline: 1.1672x; 1.0020x over previous
//
#include <hip/hip_runtime.h>

// Problem constants (from reference): B=16, L=4096, D=1024, K=64
#define Bn 16
#define Ln 4096
#define Dn 1024
#define Kn 64
#define CH 16                  // tokens per fine chunk (slot granularity)
#define SEGTOK 128             // tokens per segment (one stream block)
#define CPS (SEGTOK / CH)      // 8 chunks per segment
#define NSEG (Ln / SEGTOK)     // 32 segments per batch row
#define SLOTS (CPS + 1)        // 9 slots: excl prefix at chunk j, slot 8 = seg total
#define NSPAN (2 * Bn * Kn)    // 2048 span ints
#define QBLK 4                 // K2: d-quarters per span (one wave each)

static __device__ __forceinline__ void acc4(float4& a, const float4 v) {
    a.x += v.x; a.y += v.y; a.z += v.z; a.w += v.w;
}
static __device__ __forceinline__ void sub4(float4& a, const float4 v) {
    a.x -= v.x; a.y -= v.y; a.z -= v.z; a.w -= v.w;
}
static __device__ __forceinline__ void acc4w(float4& a, const float4 v, float w) {
    a.x += v.x * w; a.y += v.y * w; a.z += v.z * w; a.w += v.w * w;
}

// 8-slot branch-free weighted edge: acc += sign * sum_{t<n, am!=0} w_t x[base+t]
static __device__ __forceinline__ void edge8(
    const float* __restrict__ xb, const int* __restrict__ amb,
    int base, int n, float sign, float4& acc) {
    int wv[8];
    int any = 0;
#pragma unroll
    for (int t = 0; t < 8; ++t) {
        const int li = (base + t < Ln) ? (base + t) : (Ln - 1);
        wv[t] = (t < n) ? amb[li] : 0;
        any |= wv[t];
    }
    if (any != 0) {
        int f = 0;
#pragma unroll
        for (int t = 7; t >= 0; --t) if (wv[t] != 0) f = t;
        int le[8];
        int lp = f;
#pragma unroll
        for (int t = 0; t < 8; ++t) { lp = (wv[t] != 0) ? t : lp; le[t] = lp; }
        float4 v[8];
#pragma unroll
        for (int t = 0; t < 8; ++t)
            v[t] = *(const float4*)(xb + (size_t)(base + le[t]) * Dn);
        float4 s0 = {0.f,0.f,0.f,0.f}, s1 = {0.f,0.f,0.f,0.f};
#pragma unroll
        for (int t = 0; t < 8; t += 2) {
            acc4w(s0, v[t],     sign * (float)wv[t]);
            acc4w(s1, v[t + 1], sign * (float)wv[t + 1]);
        }
        acc4(s0, s1);
        acc4(acc, s0);
    }
}

// ---------------------------------------------------------------------------
// K1 (fused stream + scan, branch-free weighted loads, int4 am loads):
// grid = B*NSEG segment blocks + B am-prefix blocks + 1 decode block.
// Segment block: per 16-token chunk, am weights loaded as 4x int4 (64B
// aligned at every chunk boundary) -- 4 VMEM instructions instead of 16.
// Effective index le[t] = last attended token <= t (cndmask chain); all 16
// row loads unconditional (duplicates hit L1), w=0 kills dup contributions.
// ---------------------------------------------------------------------------
__global__ __launch_bounds__(256) void fused_stage1_kernel(
    const float* __restrict__ x, const int* __restrict__ am,
    const unsigned int* __restrict__ spans_raw,
    float* __restrict__ Pf, int* __restrict__ Pam, int* __restrict__ dec) {
    const int bc = blockIdx.x;

    if (bc < Bn * NSEG) {
        const int b = bc / NSEG;
        const int seg = bc % NSEG;
        const int d0 = threadIdx.x * 4;

        const float* xp = x + ((size_t)b * Ln + (size_t)seg * SEGTOK) * Dn + d0;
        const int4* amp4 = (const int4*)(am + b * Ln + seg * SEGTOK);
        float* pf = Pf + (size_t)bc * SLOTS * Dn + d0;

        float4 acc = {0.f, 0.f, 0.f, 0.f};
#pragma unroll
        for (int j = 0; j < CPS; ++j) {
            *(float4*)(pf + (size_t)j * Dn) = acc;   // exclusive prefix slot j

            // am weights for this chunk: 4 x int4 (vectorized)
            int4 a0 = amp4[j * 4 + 0];
            int4 a1 = amp4[j * 4 + 1];
            int4 a2 = amp4[j * 4 + 2];
            int4 a3 = amp4[j * 4 + 3];
            int wv[CH] = {a0.x, a0.y, a0.z, a0.w, a1.x, a1.y, a1.z, a1.w,
                          a2.x, a2.y, a2.z, a2.w, a3.x, a3.y, a3.z, a3.w};

            int any = 0;
#pragma unroll
            for (int t = 0; t < CH; ++t) any |= wv[t];

            if (any != 0) {                          // ~always taken
                int f = 0;
#pragma unroll
                for (int t = CH - 1; t >= 0; --t) if (wv[t] != 0) f = t;
                int le[CH];
                int lp = f;
#pragma unroll
                for (int t = 0; t < CH; ++t) {
                    lp = (wv[t] != 0) ? t : lp;
                    le[t] = lp;
                }
                float4 v[CH];
#pragma unroll
                for (int t = 0; t < CH; ++t)
                    v[t] = *(const float4*)(xp + (size_t)(j * CH + le[t]) * Dn);
                float4 s0 = {0.f, 0.f, 0.f, 0.f}, s1 = {0.f, 0.f, 0.f, 0.f};
#pragma unroll
                for (int t = 0; t < CH; t += 2) {
                    acc4w(s0, v[t],     (float)wv[t]);
                    acc4w(s1, v[t + 1], (float)wv[t + 1]);
                }
                acc4(s0, s1);
                acc4(acc, s0);
            }
        }
        *(float4*)(pf + (size_t)CPS * Dn) = acc;     // segment total
    } else if (bc < Bn * NSEG + Bn) {
        // ---- am token-prefix for batch b ----
        const int b = bc - Bn * NSEG;
        const int t = threadIdx.x;
        const int i0 = t * 16;
        const int* amb = am + (size_t)b * Ln;
        int loc[16];
        int lsum = 0;
#pragma unroll
        for (int j = 0; j < 16; ++j) { loc[j] = amb[i0 + j]; lsum += loc[j]; }

        __shared__ int ssum[256];
        ssum[t] = lsum;
        __syncthreads();
        for (int off = 1; off < 256; off <<= 1) {
            int v2 = (t >= off) ? ssum[t - off] : 0;
            __syncthreads();
            ssum[t] += v2;
            __syncthreads();
        }
        int run = ssum[t] - lsum;                    // exclusive offset
        int* pam = Pam + (size_t)b * (Ln + 1);
#pragma unroll
        for (int j = 0; j < 16; ++j) { pam[i0 + j] = run; run += loc[j]; }
        if (t == 255) pam[Ln] = run;
    } else {
        // ---- span decode ----
        __shared__ unsigned int sred[256];
        unsigned int acc = 0;
        for (int i = threadIdx.x; i < NSPAN / 2; i += 256)
            acc |= spans_raw[2 * i + 1];
        sred[threadIdx.x] = acc;
        __syncthreads();
        for (int off = 128; off > 0; off >>= 1) {
            if ((int)threadIdx.x < off) sred[threadIdx.x] |= sred[threadIdx.x + off];
            __syncthreads();
        }
        const bool is64 = (sred[0] == 0u);
        for (int i = threadIdx.x; i < NSPAN; i += 256)
            dec[i] = is64 ? (int)spans_raw[2 * i] : (int)spans_raw[i];
    }
}

// ---------------------------------------------------------------------------
// K2: per-span pooling, ONE WAVE PER D-QUARTER (identical to R16).
// ---------------------------------------------------------------------------
__global__ __launch_bounds__(64) void span_pool_kernel(
    const float* __restrict__ x, const int* __restrict__ am,
    const int* __restrict__ spans, const float* __restrict__ Pf,
    const int* __restrict__ Pam, float* __restrict__ H,
    float* __restrict__ sent_mask) {
    const int gb = blockIdx.x;
    const int bk = gb >> 2;             // span id: b*K + k
    const int q  = gb & 3;              // d-quarter
    const int b = bk / Kn;

    int s = spans[2 * bk];
    int e = spans[2 * bk + 1];
    if (s < 0) s = 0; if (s > Ln) s = Ln;
    if (e < 0) e = 0; if (e > Ln) e = Ln;
    const int len = (e > s) ? (e - s) : 0;
    if (e < s) e = s;

    const int* pam = Pam + (size_t)b * (Ln + 1);
    const int msum = pam[e] - pam[s];
    const bool use_am = (msum > 0);
    const bool valid = (len > 0);

    const int d0 = q * 256 + (int)threadIdx.x * 4;
    const float* xb = x + (size_t)b * Ln * Dn + d0;
    const int* amb = am + (size_t)b * Ln;
    float4 acc = {0.f, 0.f, 0.f, 0.f};

    if (!use_am) {
        // rare: no attended tokens in span -> plain mean over [s,e)
        for (int l = s; l < e; ++l)
            acc4(acc, *(const float4*)(xb + (size_t)l * Dn));
    } else {
        const int ca = (s + CH - 1) / CH;
        const int cb = e / CH;
        const float* Pb = Pf + (size_t)b * NSEG * SLOTS * Dn + d0;

        if (ca <= cb) {
            // ---- interior [ca*CH, cb*CH) from prefix slots ----
            if (cb > ca) {
                const int sa = ca / CPS, ja = ca % CPS;
                const int sb = cb / CPS, jb = cb % CPS;
                if (sa == sb) {
                    float4 r = *(const float4*)(Pb + (size_t)(sa * SLOTS + jb) * Dn);
                    sub4(r, *(const float4*)(Pb + (size_t)(sa * SLOTS + ja) * Dn));
                    acc4(acc, r);
                } else {
                    float4 r = *(const float4*)(Pb + (size_t)(sa * SLOTS + CPS) * Dn);
                    sub4(r, *(const float4*)(Pb + (size_t)(sa * SLOTS + ja) * Dn));
                    float4 m0 = {0.f,0.f,0.f,0.f}, m1 = {0.f,0.f,0.f,0.f};
                    int ss = sa + 1;
                    for (; ss + 1 < sb; ss += 2) {
                        acc4(m0, *(const float4*)(Pb + (size_t)(ss * SLOTS + CPS) * Dn));
                        acc4(m1, *(const float4*)(Pb + (size_t)((ss + 1) * SLOTS + CPS) * Dn));
                    }
                    if (ss < sb)
                        acc4(m0, *(const float4*)(Pb + (size_t)(ss * SLOTS + CPS) * Dn));
                    acc4(r, m0); acc4(r, m1);
                    if (jb > 0)
                        acc4(r, *(const float4*)(Pb + (size_t)(sb * SLOTS + jb) * Dn));
                    acc4(acc, r);
                }
            }

            // ---- side A: [s, ca*CH), elenA in [0,15] ----
            const int elenA = ca * CH - s;
            if (elenA > 0) {
                if (elenA <= 8) {
                    edge8(xb, amb, s, elenA, 1.f, acc);
                } else {
                    const int g = ca - 1;
                    const int sg = g / CPS, j = g % CPS;
                    acc4(acc, *(const float4*)(Pb + (size_t)(sg * SLOTS + j + 1) * Dn));
                    sub4(acc, *(const float4*)(Pb + (size_t)(sg * SLOTS + j) * Dn));
                    edge8(xb, amb, g * CH, CH - elenA, -1.f, acc);
                }
            }

            // ---- side B: [cb*CH, e), elenB in [0,15] ----
            const int elenB = e - cb * CH;
            if (elenB > 0) {
                if (elenB <= 8) {
                    edge8(xb, amb, cb * CH, elenB, 1.f, acc);
                } else {
                    const int g = cb;
                    const int sg = g / CPS, j = g % CPS;
                    acc4(acc, *(const float4*)(Pb + (size_t)(sg * SLOTS + j + 1) * Dn));
                    sub4(acc, *(const float4*)(Pb + (size_t)(sg * SLOTS + j) * Dn));
                    edge8(xb, amb, e, CH - elenB, -1.f, acc);
                }
            }
        } else {
            // span strictly inside one chunk (len <= 15): 16-slot direct
            int wv[CH];
#pragma unroll
            for (int t = 0; t < CH; ++t) {
                const int li = (s + t < Ln) ? (s + t) : (Ln - 1);
                wv[t] = (t < len) ? amb[li] : 0;
            }
            int any = 0;
#pragma unroll
            for (int t = 0; t < CH; ++t) any |= wv[t];
            if (any != 0) {
                int f = 0;
#pragma unroll
                for (int t = CH - 1; t >= 0; --t) if (wv[t] != 0) f = t;
                int le[CH];
                int lp = f;
#pragma unroll
                for (int t = 0; t < CH; ++t) {
                    lp = (wv[t] != 0) ? t : lp;
                    le[t] = lp;
                }
                float4 v[CH];
#pragma unroll
                for (int t = 0; t < CH; ++t)
                    v[t] = *(const float4*)(xb + (size_t)(s + le[t]) * Dn);
                float4 s0 = {0.f,0.f,0.f,0.f}, s1 = {0.f,0.f,0.f,0.f};
#pragma unroll
                for (int t = 0; t < CH; t += 2) {
                    acc4w(s0, v[t],     (float)wv[t]);
                    acc4w(s1, v[t + 1], (float)wv[t + 1]);
                }
                acc4(s0, s1);
                acc4(acc, s0);
            }
        }
    }

    const float denom = use_am ? (float)msum : (float)len;
    const float inv = valid ? (1.0f / denom) : 0.0f;
    float4 outv;
    outv.x = acc.x * inv; outv.y = acc.y * inv;
    outv.z = acc.z * inv; outv.w = acc.w * inv;

    *(float4*)(H + (size_t)bk * Dn + d0) = outv;
    if (threadIdx.x == 0 && q == 0) sent_mask[bk] = valid ? 1.0f : 0.0f;
}

extern "C" void kernel_launch(void* const* d_in, const int* in_sizes, int n_in,
                              void* d_out, int out_size, void* d_ws, size_t ws_size,
                              hipStream_t stream) {
    const float* x = (const float*)d_in[0];
    const int* am = (const int*)d_in[1];
    const unsigned int* spans_raw = (const unsigned int*)d_in[2];

    float* H = (float*)d_out;
    float* sent_mask = H + (size_t)Bn * Kn * Dn;

    // workspace layout: dec | Pam | Pf
    const size_t dec_bytes = 8192;                                 // >= NSPAN*4
    const size_t pam_bytes = (size_t)Bn * (Ln + 1) * sizeof(int);  // 262208 B
    int* dec = (int*)d_ws;
    int* Pam = (int*)((char*)d_ws + dec_bytes);
    float* Pf = (float*)((char*)d_ws + dec_bytes + pam_bytes);     // ~18.9 MB

    fused_stage1_kernel<<<Bn * NSEG + Bn + 1, 256, 0, stream>>>(
        x, am, spans_raw, Pf, Pam, dec);
    span_pool_kernel<<<Bn * Kn * QBLK, 64, 0, stream>>>(
        x, am, dec, Pf, Pam, H, sent_mask);
}